// Round 6
// baseline (8452.818 us; speedup 1.0000x reference)
//
#include <hip/hip_runtime.h>
#include <math.h>

#define N_IN   65536
#define N_UP   262144
#define N_OUT  131072
#define K1     27
#define K2     27
#define K3     16
#define KM1    (27 * 65536)
#define KM2    (27 * 131072)
#define KM3    (16 * 131072)
#define EPSV   1e-6f
#define BROWS  128
#define BCAP   3584
#define QSCALE 4194304.0f            // 2^22 fixed-point for y accumulation
#define QINV   (1.0f / 4194304.0f)
#define SSCALE 1048576.0             // 2^20 fixed-point for stats sums

typedef unsigned long long u64;

// ---------------- counting-sort pipeline (per conv) ----------------

__global__ __launch_bounds__(256) void hist_kernel(
    const int* __restrict__ kout, int km, int* __restrict__ counts)
{
    for (int j = blockIdx.x * 256 + threadIdx.x; j < km; j += gridDim.x * 256)
        atomicAdd(&counts[kout[j]], 1);
}

__global__ __launch_bounds__(256) void scan_partial(
    int* __restrict__ a, int* __restrict__ bsums)
{
    __shared__ int sa[256], sb[256];
    const int t = threadIdx.x;
    int4 v = ((const int4*)a)[blockIdx.x * 256 + t];
    const int s = v.x + v.y + v.z + v.w;
    sa[t] = s; __syncthreads();
    int* src = sa; int* dst = sb;
    for (int off = 1; off < 256; off <<= 1) {
        dst[t] = (t >= off) ? src[t - off] + src[t] : src[t];
        __syncthreads();
        int* tmp = src; src = dst; dst = tmp;
    }
    const int incl = src[t];
    const int excl = incl - s;
    int4 o;
    o.x = excl; o.y = excl + v.x; o.z = o.y + v.y; o.w = o.z + v.z;
    ((int4*)a)[blockIdx.x * 256 + t] = o;
    if (t == 255) bsums[blockIdx.x] = incl;
}

__global__ void scan_top(int* __restrict__ bsums, int nb)
{
    __shared__ int sa[256], sb[256];
    const int t = threadIdx.x;
    const int s = (t < nb) ? bsums[t] : 0;
    sa[t] = s; __syncthreads();
    int* src = sa; int* dst = sb;
    for (int off = 1; off < 256; off <<= 1) {
        dst[t] = (t >= off) ? src[t - off] + src[t] : src[t];
        __syncthreads();
        int* tmp = src; src = dst; dst = tmp;
    }
    if (t < nb) bsums[t] = src[t] - s;
}

__global__ __launch_bounds__(256) void add_off(
    int* __restrict__ rs, const int* __restrict__ bsums,
    int* __restrict__ cursor, int n, int km)
{
    const int i = blockIdx.x * 256 + threadIdx.x;
    const int v = rs[i] + bsums[i >> 10];
    rs[i] = v; cursor[i] = v;
    if (i == 0) rs[n] = km;
}

__global__ __launch_bounds__(256) void scatter_kernel(
    const int* __restrict__ kin, const int* __restrict__ kout,
    int* __restrict__ cursor, unsigned* __restrict__ sorted,
    int km, int mshift)
{
    for (int j = blockIdx.x * 256 + threadIdx.x; j < km; j += gridDim.x * 256) {
        const int pos = atomicAdd(&cursor[kout[j]], 1);
        sorted[pos] = (unsigned)kin[j] | ((unsigned)(j >> mshift) << 18);
    }
}

// ---------------- sorted conv: deterministic int32 LDS accumulation ----------------
// Block owns 128 dst rows. Entries bucketed by k (order-free: integer adds are
// exactly associative). Full 64-entry batches + 16-entry quarter-tails,
// flattened across the 4 waves via prefix + binary search.

template <int CIN, int K>
__global__ __launch_bounds__(256) void conv_sorted(
    const float* __restrict__ X, const float* __restrict__ W,
    const int* __restrict__ rowst, const unsigned* __restrict__ sorted,
    float* __restrict__ outp, u64* __restrict__ stats_i)
{
    __shared__ int      y[BROWS * 65];
    __shared__ unsigned bkt[BCAP];
    __shared__ int      rs[BROWS + 1];
    __shared__ int      bc[28], bs[28], bcur[28], fpre[29], qpre[29];
    __shared__ float    sred[256], sred2[256];

    const int t    = threadIdx.x;
    const int lane = t & 63;
    const int wv   = t >> 6;
    const int r0   = blockIdx.x * BROWS;

    for (int i = t; i < BROWS * 65; i += 256) y[i] = 0;
    if (t < 28) bc[t] = 0;
    if (t <= BROWS) rs[t] = rowst[r0 + t];
    __syncthreads();

    const int p0 = rs[0], p1 = rs[BROWS];

    for (int p = p0 + t; p < p1; p += 256)
        atomicAdd(&bc[sorted[p] >> 18], 1);
    __syncthreads();
    if (t == 0) {
        int run = 0, fr = 0, qr = 0;
        for (int k = 0; k < K; ++k) {
            bs[k] = run; bcur[k] = run; run += bc[k];
            fpre[k] = fr; fr += bc[k] >> 6;
            qpre[k] = qr; qr += ((bc[k] & 63) + 15) >> 4;
        }
        fpre[K] = fr; qpre[K] = qr;
    }
    __syncthreads();
    for (int p = p0 + t; p < p1; p += 256) {
        const unsigned e = sorted[p];
        const int k = e >> 18;
        int lo = 0, hi = BROWS;
        while (hi - lo > 1) { const int mid = (lo + hi) >> 1; if (rs[mid] <= p) lo = mid; else hi = mid; }
        const int pos = atomicAdd(&bcur[k], 1);
        if (pos < BCAP) bkt[pos] = (e & 0x3FFFFu) | ((unsigned)lo << 18);
    }
    __syncthreads();

    constexpr int KC = CIN / 16;

    // ---- phase 1: full 64-entry batches, k-uniform (W via scalar broadcast)
    const int nf = fpre[K];
    for (int fb = wv; fb < nf; fb += 4) {
        int lo = 0, hi = K;
        while (hi - lo > 1) { const int mid = (lo + hi) >> 1; if (fpre[mid] <= fb) lo = mid; else hi = mid; }
        const int k = lo, b = fb - fpre[k];
        const unsigned e = bkt[bs[k] + b * 64 + lane];
        const int src = e & 0x3FFFFu;
        const int ld  = e >> 18;
        const float* Wk = W + (size_t)k * (CIN * 64);
        const float4* xr = (const float4*)(X + (size_t)src * CIN);

        float acc[64];
#pragma unroll
        for (int c = 0; c < 64; ++c) acc[c] = 0.f;

        float4 xa0 = xr[0], xa1 = xr[1], xa2 = xr[2], xa3 = xr[3];

        for (int kc = 0; kc < KC; ++kc) {
            float4 xb0, xb1, xb2, xb3;
            if (kc + 1 < KC) {
                xb0 = xr[(kc + 1) * 4 + 0];
                xb1 = xr[(kc + 1) * 4 + 1];
                xb2 = xr[(kc + 1) * 4 + 2];
                xb3 = xr[(kc + 1) * 4 + 3];
            }
            float xs[16];
            xs[0]=xa0.x; xs[1]=xa0.y; xs[2]=xa0.z; xs[3]=xa0.w;
            xs[4]=xa1.x; xs[5]=xa1.y; xs[6]=xa1.z; xs[7]=xa1.w;
            xs[8]=xa2.x; xs[9]=xa2.y; xs[10]=xa2.z; xs[11]=xa2.w;
            xs[12]=xa3.x; xs[13]=xa3.y; xs[14]=xa3.z; xs[15]=xa3.w;

            const float* wrow = Wk + kc * 16 * 64;
#pragma unroll
            for (int i = 0; i < 16; ++i) {
                const float xi = xs[i];
                const float* wr = wrow + i * 64;   // wave-uniform -> s_load
#pragma unroll
                for (int c = 0; c < 64; ++c)
                    acc[c] = fmaf(xi, wr[c], acc[c]);
            }
            xa0 = xb0; xa1 = xb1; xa2 = xb2; xa3 = xb3;
        }

        int* yr = &y[ld * 65];
#pragma unroll
        for (int c = 0; c < 64; ++c)
            atomicAdd(&yr[c], (int)rintf(acc[c] * QSCALE));   // order-free
    }

    // ---- phase 2: 16-entry quarter-tails (lane = entry[0:16) x ch-quarter)
    const int nq = qpre[K];
    const int cq = lane >> 4;
    for (int qb = wv; qb < nq; qb += 4) {
        int lo = 0, hi = K;
        while (hi - lo > 1) { const int mid = (lo + hi) >> 1; if (qpre[mid] <= qb) lo = mid; else hi = mid; }
        const int k = lo, tq = qb - qpre[k];
        const int tbase = bs[k] + (bc[k] & ~63);
        const int tcnt  = bc[k] & 63;
        const int ei = tq * 16 + (lane & 15);
        const bool valid = ei < tcnt;
        const unsigned e = valid ? bkt[tbase + ei] : 0u;
        const int src = e & 0x3FFFFu;
        const int ld  = e >> 18;
        const float4* x4 = (const float4*)(X + (size_t)src * CIN);
        const float*  wq = W + (size_t)k * (CIN * 64) + cq * 16;
        const float4  z4 = make_float4(0.f, 0.f, 0.f, 0.f);

        float acc[16];
#pragma unroll
        for (int c = 0; c < 16; ++c) acc[c] = 0.f;

        for (int i4 = 0; i4 < CIN / 4; ++i4) {
            const float4 xv = valid ? x4[i4] : z4;
            const float xs4[4] = { xv.x, xv.y, xv.z, xv.w };
#pragma unroll
            for (int j = 0; j < 4; ++j) {
                const float xi = xs4[j];
                const float* wr = wq + (i4 * 4 + j) * 64;
#pragma unroll
                for (int c = 0; c < 16; ++c)
                    acc[c] = fmaf(xi, wr[c], acc[c]);
            }
        }
        if (valid) {
            int* yr = &y[ld * 65 + cq * 16];
#pragma unroll
            for (int c = 0; c < 16; ++c)
                atomicAdd(&yr[c], (int)rintf(acc[c] * QSCALE));
        }
    }
    __syncthreads();

    // ---- exclusive writeout + deterministic instance-norm partials
    float s = 0.f, s2 = 0.f;
    for (int i = t; i < BROWS * 64; i += 256) {
        const int row = i >> 6, c = i & 63;
        const float v = (float)y[row * 65 + c] * QINV;
        outp[(size_t)(r0 + row) * 64 + c] = v;
        s += v; s2 = fmaf(v, v, s2);
    }
    sred[t] = s; sred2[t] = s2;
    __syncthreads();
    if (t < 64) {
        s  = (sred[t] + sred[t + 64]) + (sred[t + 128] + sred[t + 192]);
        s2 = (sred2[t] + sred2[t + 64]) + (sred2[t + 128] + sred2[t + 192]);
        const long long qs  = llrint((double)s  * SSCALE);
        const long long qs2 = llrint((double)s2 * SSCALE);
        atomicAdd(&stats_i[t],      (u64)qs);    // integer: order-free
        atomicAdd(&stats_i[64 + t], (u64)qs2);
    }
}

// ---------------- norm / epilogue ----------------

__global__ void finalize_stats(const u64* __restrict__ si,
                               float* __restrict__ sf, double inv_n)
{
    const int c = threadIdx.x;   // 64
    const double sum  = (double)(long long)si[c]      * (1.0 / SSCALE);
    const double sum2 = (double)(long long)si[64 + c] * (1.0 / SSCALE);
    const double mu   = sum * inv_n;
    const double var  = sum2 * inv_n - mu * mu;
    sf[c]      = (float)mu;
    sf[64 + c] = rsqrtf((float)(var + (double)EPSV));
}

__global__ __launch_bounds__(256) void norm_elu(
    float* __restrict__ x, const float* __restrict__ sf,
    const float* __restrict__ enc)
{
    const int i = blockIdx.x * 256 + threadIdx.x;
    const int c = i & 63;
    float v = (x[i] - sf[c]) * sf[64 + c];
    v = (v > 0.f) ? v : expm1f(v);
    if (enc) v += enc[i];
    x[i] = v;
}

__global__ __launch_bounds__(256) void final_kernel(
    const float* __restrict__ x, const float* __restrict__ sf,
    const float* __restrict__ Wp, const float* __restrict__ bp,
    float* __restrict__ outp)
{
    const int lane = threadIdx.x & 63;
    const int row  = blockIdx.x * 4 + (threadIdx.x >> 6);

    float v = (x[(size_t)row * 64 + lane] - sf[lane]) * sf[64 + lane];
    v = (v > 0.f) ? v : expm1f(v);

    float p = v * Wp[lane];
#pragma unroll
    for (int m = 1; m < 64; m <<= 1)
        p += __shfl_xor(p, m, 64);
    p += bp[0];

    const bool keep = p > 0.0f;
    outp[(size_t)row * 64 + lane] = keep ? v : 0.f;
    if (lane == 0)
        outp[(size_t)N_OUT * 64 + row] = keep ? 1.f : 0.f;
}

// ---------------- launch ----------------

extern "C" void kernel_launch(void* const* d_in, const int* in_sizes, int n_in,
                              void* d_out, int out_size, void* d_ws, size_t ws_size,
                              hipStream_t stream)
{
    const float* in_feats = (const float*)d_in[0];
    const float* enc      = (const float*)d_in[1];
    const float* W1       = (const float*)d_in[2];
    const float* W2       = (const float*)d_in[3];
    const float* W3       = (const float*)d_in[4];
    const float* Wp       = (const float*)d_in[5];
    const float* bp       = (const float*)d_in[6];
    const int* kin1  = (const int*)d_in[7];
    const int* kout1 = (const int*)d_in[8];
    const int* kin2  = (const int*)d_in[9];
    const int* kout2 = (const int*)d_in[10];
    const int* kin3  = (const int*)d_in[11];
    const int* kout3 = (const int*)d_in[12];
    float* outp = (float*)d_out;

    char* ws = (char*)d_ws;
    float*    up_a  = (float*)ws;                       // 64 MB
    float*    up_b  = (float*)(ws + 67108864);          // 64 MB
    float*    out3  = up_a;                             // reuse
    u64*      siA   = (u64*)(ws + 134217728);           // 128 i64 each
    u64*      siB   = (u64*)(ws + 134219776);
    u64*      siC   = (u64*)(ws + 134221824);
    float*    sfA   = (float*)(ws + 134223872);         // 128 f32 each
    float*    sfB   = sfA + 128;
    float*    sfC   = sfA + 256;
    int*      rs    = (int*)(ws + 134230016);           // (N_UP+1) ints
    int*      cur   = (int*)(ws + 135282688);           // (N_UP+1) ints
    int*      bsums = (int*)(ws + 136331264);           // 256 ints
    unsigned* sorted = (unsigned*)(ws + 136335360);     // KM2 u32 = 14.2 MB

    hipMemsetAsync(siA, 0, 3 * 2048, stream);

    // ---- conv1: in_feats[65536,128] -> up_a[262144,64]
    hipMemsetAsync(rs, 0, (N_UP + 1) * 4, stream);
    hist_kernel<<<1024, 256, 0, stream>>>(kout1, KM1, rs);
    scan_partial<<<N_UP / 1024, 256, 0, stream>>>(rs, bsums);
    scan_top<<<1, 256, 0, stream>>>(bsums, N_UP / 1024);
    add_off<<<N_UP / 256, 256, 0, stream>>>(rs, bsums, cur, N_UP, KM1);
    scatter_kernel<<<1024, 256, 0, stream>>>(kin1, kout1, cur, sorted, KM1, 16);
    conv_sorted<128, K1><<<N_UP / BROWS, 256, 0, stream>>>(
        in_feats, W1, rs, sorted, up_a, siA);
    finalize_stats<<<1, 64, 0, stream>>>(siA, sfA, 1.0 / N_UP);
    norm_elu<<<(N_UP * 64) / 256, 256, 0, stream>>>(up_a, sfA, nullptr);

    // ---- conv2: up_a -> up_b
    hipMemsetAsync(rs, 0, (N_UP + 1) * 4, stream);
    hist_kernel<<<1024, 256, 0, stream>>>(kout2, KM2, rs);
    scan_partial<<<N_UP / 1024, 256, 0, stream>>>(rs, bsums);
    scan_top<<<1, 256, 0, stream>>>(bsums, N_UP / 1024);
    add_off<<<N_UP / 256, 256, 0, stream>>>(rs, bsums, cur, N_UP, KM2);
    scatter_kernel<<<1024, 256, 0, stream>>>(kin2, kout2, cur, sorted, KM2, 17);
    conv_sorted<64, K2><<<N_UP / BROWS, 256, 0, stream>>>(
        up_a, W2, rs, sorted, up_b, siB);
    finalize_stats<<<1, 64, 0, stream>>>(siB, sfB, 1.0 / N_UP);
    norm_elu<<<(N_UP * 64) / 256, 256, 0, stream>>>(up_b, sfB, enc);  // + skip

    // ---- conv3: up_b -> out3 (= up_a storage)
    hipMemsetAsync(rs, 0, (N_OUT + 1) * 4, stream);
    hist_kernel<<<1024, 256, 0, stream>>>(kout3, KM3, rs);
    scan_partial<<<N_OUT / 1024, 256, 0, stream>>>(rs, bsums);
    scan_top<<<1, 256, 0, stream>>>(bsums, N_OUT / 1024);
    add_off<<<N_OUT / 256, 256, 0, stream>>>(rs, bsums, cur, N_OUT, KM3);
    scatter_kernel<<<1024, 256, 0, stream>>>(kin3, kout3, cur, sorted, KM3, 17);
    conv_sorted<64, K3><<<N_OUT / BROWS, 256, 0, stream>>>(
        up_b, W3, rs, sorted, out3, siC);
    finalize_stats<<<1, 64, 0, stream>>>(siC, sfC, 1.0 / N_OUT);

    // ---- pruning head
    final_kernel<<<N_OUT / 4, 256, 0, stream>>>(out3, sfC, Wp, bp, outp);
}